// Round 6
// baseline (296.839 us; speedup 1.0000x reference)
//
#include <hip/hip_runtime.h>
#include <cstddef>

#define NN 100000
#define DD 128
#define ND (NN * DD)
#define BN_EPS 1e-5f
#define LDA 136                // LDS A row stride in bf16 elems (272 B, 16B-aligned)
#define NREP 64                // stats-accumulator replicas
#define NB 391                 // destination buckets of 256 nodes (391*256 >= NN)
#define S1E 16                 // edges per thread in k_scat1

typedef __bf16 bf16_t;
typedef bf16_t bf16x8 __attribute__((ext_vector_type(8)));
typedef float f32x4 __attribute__((ext_vector_type(4)));
typedef unsigned int uint;
typedef unsigned short ushort;

// ws 4-byte-slot layout:
//   [0, ND/2)            hb   (bf16 h, [NN][128])
//   [ND/2, ND)           xb   (bf16 x)
//   [ND, 3ND/2)          aggb (bf16 S*x)
//   then: csr[64*128] (zeroed), cqr[64*128] (zeroed), cnt[NN] (zeroed),
//         colsum[128], colsumsq[128], bptr[400], bcur[400], ptr0[NN],
//         ebuck[E], srow[E], wb[8192 uints]

__device__ __forceinline__ ushort f2b(float f) {
    uint u = __builtin_bit_cast(uint, f);
    u += 0x7FFFu + ((u >> 16) & 1u);          // RNE
    return (ushort)(u >> 16);
}
__device__ __forceinline__ float b2f(uint s) {
    return __builtin_bit_cast(float, s << 16);
}

// int64 edge_index => high word of every entry is 0 (ids < 100000).
__device__ __forceinline__ int detect_i64(const int* __restrict__ ei) {
    __shared__ int sflag;
    int t = threadIdx.x;
    if (t < 64) {
        int hi = ei[2 * t + 1];
        unsigned long long b = __ballot(hi == 0);
        if (t == 0) sflag = (b == ~0ull) ? 1 : 0;
    }
    __syncthreads();
    return sflag;
}

// dual-role: blocks [0, nbh) histogram destination degrees; rest pack x, W to bf16
__global__ __launch_bounds__(256) void k_prep(const int* __restrict__ ei,
                                              int* __restrict__ cnt, int E, int nbh,
                                              const float* __restrict__ x,
                                              uint* __restrict__ xb,
                                              const float* __restrict__ W,
                                              uint* __restrict__ wb) {
    if ((int)blockIdx.x < nbh) {
        int f = detect_i64(ei);
        int e = blockIdx.x * 256 + threadIdx.x;
        if (e >= E) return;
        int c = f ? ei[2 * (E + e)] : ei[E + e];
        atomicAdd(&cnt[c], 1);
        return;
    }
    int i = (blockIdx.x - nbh) * 256 + threadIdx.x;
    const float* src;
    uint* dst;
    int j;
    if (i < ND / 8) { src = x; dst = xb; j = i; }
    else { j = i - ND / 8; if (j >= (DD * DD) / 8) return; src = W; dst = wb; }
    const float4* s4 = (const float4*)src;
    float4 a = s4[2 * j], b = s4[2 * j + 1];
    uint4 o;
    o.x = (uint)f2b(a.x) | ((uint)f2b(a.y) << 16);
    o.y = (uint)f2b(a.z) | ((uint)f2b(a.w) << 16);
    o.z = (uint)f2b(b.x) | ((uint)f2b(b.y) << 16);
    o.w = (uint)f2b(b.z) | ((uint)f2b(b.w) << 16);
    ((uint4*)dst)[j] = o;
}

// bucket sums from cnt + exclusive scan -> bptr[NB+1], bcur (working cursors)
__global__ __launch_bounds__(1024) void k_scanB(const int* __restrict__ cnt,
                                                int* __restrict__ bptr,
                                                int* __restrict__ bcur) {
    __shared__ int bs[NB + 1];
    int t = threadIdx.x;
    int g = t >> 6, lane = t & 63;
    for (int b = g; b < NB; b += 16) {
        int base = b << 8;
        int s = 0;
#pragma unroll
        for (int q = 0; q < 4; ++q) {
            int idx = base + lane + q * 64;
            if (idx < NN) s += cnt[idx];
        }
        for (int o = 1; o < 64; o <<= 1) s += __shfl_xor(s, o);
        if (lane == 0) bs[b] = s;
    }
    __syncthreads();
    if (t == 0) {
        int run = 0;
        for (int i = 0; i < NB; ++i) { int v = bs[i]; bs[i] = run; run += v; }
        bs[NB] = run;
    }
    __syncthreads();
    if (t <= NB) {
        bptr[t] = bs[t];
        if (t < NB) bcur[t] = bs[t];
    }
}

// phase 1: group edges by 256-node destination bucket.
// rec = (c_local[8b] << 17) | src[17b]
__global__ __launch_bounds__(256) void k_scat1(const int* __restrict__ ei, int E,
                                               int* __restrict__ bcur,
                                               uint* __restrict__ ebuck) {
    __shared__ int lh[NB], gb[NB];
    int f = detect_i64(ei);
    int t = threadIdx.x;
    for (int i = t; i < NB; i += 256) lh[i] = 0;
    __syncthreads();
    int bk[S1E]; uint rec[S1E];
    int e0 = blockIdx.x * (S1E * 256);
#pragma unroll
    for (int i = 0; i < S1E; ++i) {
        int e = e0 + i * 256 + t;
        bk[i] = -1;
        rec[i] = 0;
        if (e < E) {
            int r, c;
            if (f) { r = ei[2 * e]; c = ei[2 * (E + e)]; }
            else   { r = ei[e];     c = ei[E + e]; }
            bk[i] = c >> 8;
            rec[i] = ((uint)(c & 255) << 17) | (uint)r;
            atomicAdd(&lh[bk[i]], 1);
        }
    }
    __syncthreads();
    for (int i = t; i < NB; i += 256) {
        int n = lh[i];
        gb[i] = n > 0 ? atomicAdd(&bcur[i], n) : 0;
    }
    __syncthreads();
    for (int i = t; i < NB; i += 256) lh[i] = 0;
    __syncthreads();
#pragma unroll
    for (int i = 0; i < S1E; ++i) {
        if (bk[i] >= 0) {
            int rk = atomicAdd(&lh[bk[i]], 1);
            ebuck[gb[bk[i]] + rk] = rec[i];
        }
    }
}

// phase 2: per-bucket counting sort to per-node order; emits srow + ptr0.
// The whole srow region [s, s+n) is written by THIS block only -> one XCD's L2
// -> full-line writeback (no cross-XCD partial-line amplification).
__global__ __launch_bounds__(256) void k_scat2(const uint* __restrict__ ebuck,
                                               const int* __restrict__ bptr,
                                               int* __restrict__ ptr0,
                                               int* __restrict__ srow) {
    __shared__ int h[256], cur[256], sc[256];
    int b = blockIdx.x;
    int t = threadIdx.x;
    int s = bptr[b];
    int n = bptr[b + 1] - s;
    h[t] = 0;
    __syncthreads();
    for (int j = t; j < n; j += 256)
        atomicAdd(&h[ebuck[s + j] >> 17], 1);
    __syncthreads();
    int own = h[t];
    sc[t] = own;
    __syncthreads();
    for (int o = 1; o < 256; o <<= 1) {
        int v = (t >= o) ? sc[t - o] : 0;
        __syncthreads();
        sc[t] += v;
        __syncthreads();
    }
    int off = sc[t] - own;            // exclusive
    cur[t] = s + off;
    int node = (b << 8) + t;
    if (node < NN) ptr0[node] = s + off;
    __syncthreads();
    for (int j = t; j < n; j += 256) {
        uint rec = ebuck[s + j];
        int p = atomicAdd(&cur[rec >> 17], 1);
        srow[p] = (int)(rec & 0x1FFFFu);
    }
}

// one wave per node; weights recomputed from cnt; xb row loads 8-deep
__global__ __launch_bounds__(256) void k_gather(const uint* __restrict__ xb,
                                                const int* __restrict__ srow,
                                                const int* __restrict__ ptr0,
                                                const int* __restrict__ cnt,
                                                uint* __restrict__ aggb) {
    int n = blockIdx.x * 4 + (threadIdx.x >> 6);
    int lane = threadIdx.x & 63;
    int s = ptr0[n];
    int k = cnt[n];
    float dc = k > 0 ? rsqrtf((float)k) : 0.f;
    float ax = 0.f, ay = 0.f;
    for (int base = 0; base < k; base += 64) {
        int m = min(k - base, 64);
        int rj = 0; float wj = 0.f;
        if (lane < m) {
            rj = srow[s + base + lane];
            int cj = cnt[rj];
            wj = cj > 0 ? rsqrtf((float)cj) : 0.f;
        }
        int j = 0;
        for (; j + 8 <= m; j += 8) {
            uint v[8]; float w[8];
#pragma unroll
            for (int q = 0; q < 8; ++q) {
                int rq = __shfl(rj, j + q);
                w[q] = __shfl(wj, j + q);
                v[q] = xb[(size_t)rq * 64 + lane];
            }
#pragma unroll
            for (int q = 0; q < 8; ++q) {
                ax = fmaf(w[q], b2f(v[q] & 0xFFFFu), ax);
                ay = fmaf(w[q], b2f(v[q] >> 16), ay);
            }
        }
        for (; j + 4 <= m; j += 4) {
            uint v[4]; float w[4];
#pragma unroll
            for (int q = 0; q < 4; ++q) {
                int rq = __shfl(rj, j + q);
                w[q] = __shfl(wj, j + q);
                v[q] = xb[(size_t)rq * 64 + lane];
            }
#pragma unroll
            for (int q = 0; q < 4; ++q) {
                ax = fmaf(w[q], b2f(v[q] & 0xFFFFu), ax);
                ay = fmaf(w[q], b2f(v[q] >> 16), ay);
            }
        }
        for (; j < m; ++j) {
            int r = __shfl(rj, j);
            float w = __shfl(wj, j);
            uint v = xb[(size_t)r * 64 + lane];
            ax = fmaf(w, b2f(v & 0xFFFFu), ax);
            ay = fmaf(w, b2f(v >> 16), ay);
        }
    }
    aggb[(size_t)n * 64 + lane] = (uint)f2b(dc * ax) | ((uint)f2b(dc * ay) << 16);
}

// hb = aggb @ W^T via MFMA bf16 + fused column stats into replicated banks.
__global__ __launch_bounds__(256, 2) void k_gemm(const ushort* __restrict__ aggb,
                                                 const ushort* __restrict__ wb,
                                                 ushort* __restrict__ hb,
                                                 float* __restrict__ csr,
                                                 float* __restrict__ cqr) {
    __shared__ ushort sA[64 * LDA];           // 17.4 KB
    __shared__ float cp[4][128], cq[4][128];  // 4 KB
    int t = threadIdx.x;
    int wave = t >> 6, lane = t & 63;
    int quad = lane >> 4, l16 = lane & 15;
    size_t rowbase = (size_t)blockIdx.x * 64;

    bf16x8 Bf[8][4];
#pragma unroll
    for (int ct = 0; ct < 8; ++ct)
#pragma unroll
        for (int ks = 0; ks < 4; ++ks) {
            const uint4* p =
                (const uint4*)(wb + (size_t)(ct * 16 + l16) * 128 + ks * 32 + quad * 8);
            Bf[ct][ks] = __builtin_bit_cast(bf16x8, *p);
        }

    // stage A (OOB rows -> zeros so fused stats stay exact)
#pragma unroll
    for (int i = 0; i < 4; ++i) {
        int c = t + i * 256;
        int r = c >> 4, pos = c & 15;
        size_t gr = rowbase + r;
        uint4 v = {0u, 0u, 0u, 0u};
        if (gr < NN) v = *(const uint4*)(aggb + gr * 128 + pos * 8);
        *(uint4*)(sA + r * LDA + pos * 8) = v;
    }
    __syncthreads();

    bf16x8 Af[4];
#pragma unroll
    for (int ks = 0; ks < 4; ++ks)
        Af[ks] = __builtin_bit_cast(
            bf16x8, *(const uint4*)(sA + (wave * 16 + l16) * LDA + ks * 32 + quad * 8));

    f32x4 acc[8];
#pragma unroll
    for (int ct = 0; ct < 8; ++ct) {
        acc[ct] = (f32x4){0.f, 0.f, 0.f, 0.f};
#pragma unroll
        for (int ks = 0; ks < 4; ++ks)
            acc[ct] = __builtin_amdgcn_mfma_f32_16x16x32_bf16(Af[ks], Bf[ct][ks],
                                                              acc[ct], 0, 0, 0);
    }

#pragma unroll
    for (int ct = 0; ct < 8; ++ct) {
        float ss = 0.f, qq = 0.f;
#pragma unroll
        for (int r = 0; r < 4; ++r) {
            float v = acc[ct][r];
            ss += v; qq += v * v;
            size_t row = rowbase + wave * 16 + quad * 4 + r;
            if (row < NN) hb[row * 128 + ct * 16 + l16] = f2b(v);
        }
        ss += __shfl_xor(ss, 16); ss += __shfl_xor(ss, 32);
        qq += __shfl_xor(qq, 16); qq += __shfl_xor(qq, 32);
        if (quad == 0) { cp[wave][ct * 16 + l16] = ss; cq[wave][ct * 16 + l16] = qq; }
    }
    __syncthreads();
    if (t < 128) {
        int rep = (blockIdx.x & (NREP - 1)) * 128 + t;
        atomicAdd(&csr[rep], cp[0][t] + cp[1][t] + cp[2][t] + cp[3][t]);
        atomicAdd(&cqr[rep], cq[0][t] + cq[1][t] + cq[2][t] + cq[3][t]);
    }
}

// fold the 64 replicas
__global__ void k_red(const float* __restrict__ csr, const float* __restrict__ cqr,
                      float* __restrict__ colsum, float* __restrict__ colsumsq) {
    int t = threadIdx.x;          // 256
    if (t < 128) {
        float s = 0.f;
        for (int i = 0; i < NREP; ++i) s += csr[i * 128 + t];
        colsum[t] = s;
    } else {
        int c = t - 128;
        float s = 0.f;
        for (int i = 0; i < NREP; ++i) s += cqr[i * 128 + c];
        colsumsq[c] = s;
    }
}

__global__ __launch_bounds__(256) void k_final(const uint* __restrict__ hb,
                                               const uint* __restrict__ xb,
                                               const float* __restrict__ gamma,
                                               const float* __restrict__ beta,
                                               const float* __restrict__ colsum,
                                               const float* __restrict__ colsumsq,
                                               float* __restrict__ out, int out_size) {
    int gid = blockIdx.x * 256 + threadIdx.x;     // 4-col group index over ND/4
    int c4 = (gid & 31) * 4;
    uint2 hv = ((const uint2*)hb)[gid];
    uint2 xv = ((const uint2*)xb)[gid];
    float hval[4] = { b2f(hv.x & 0xFFFFu), b2f(hv.x >> 16),
                      b2f(hv.y & 0xFFFFu), b2f(hv.y >> 16) };
    float xval[4] = { b2f(xv.x & 0xFFFFu), b2f(xv.x >> 16),
                      b2f(xv.y & 0xFFFFu), b2f(xv.y >> 16) };
    const float invN = 1.0f / NN;
    float4 o;
    float res[4];
#pragma unroll
    for (int j = 0; j < 4; ++j) {
        float m = colsum[c4 + j] * invN;
        float var = colsumsq[c4 + j] * invN - m * m;
        float inv = rsqrtf(var + BN_EPS);
        float val = (hval[j] - m) * inv * gamma[c4 + j] + beta[c4 + j];
        res[j] = fmaxf(val, 0.f) + xval[j];
    }
    o.x = res[0]; o.y = res[1]; o.z = res[2]; o.w = res[3];
    ((float4*)out)[gid] = o;
    if (gid == 0 && out_size > ND) out[ND] = 0.0f;
}

extern "C" void kernel_launch(void* const* d_in, const int* in_sizes, int n_in,
                              void* d_out, int out_size, void* d_ws, size_t ws_size,
                              hipStream_t stream) {
    const float* x     = (const float*)d_in[0];
    const int*   ei    = (const int*)d_in[1];
    const float* W     = (const float*)d_in[2];
    const float* gamma = (const float*)d_in[4];
    const float* beta  = (const float*)d_in[5];
    float* ws = (float*)d_ws;
    float* out = (float*)d_out;

    uint*   hb       = (uint*)ws;
    uint*   xb       = hb + ND / 2;
    uint*   aggb     = xb + ND / 2;
    float*  csr      = (float*)(aggb + ND / 2);        // 64*128
    float*  cqr      = csr + NREP * 128;               // 64*128
    int*    cnt      = (int*)(cqr + NREP * 128);
    float*  colsum   = (float*)(cnt + NN);
    float*  colsumsq = colsum + 128;
    int*    bptr     = (int*)(colsumsq + 128);         // 400 slots
    int*    bcur     = bptr + 400;                     // 400 slots
    int*    ptr0     = bcur + 400;

    int E = in_sizes[1] / 2;
    uint*   ebuck    = (uint*)(ptr0 + NN);
    int*    srow     = (int*)(ebuck + E);
    uint*   wb       = (uint*)(srow + E);

    int nbh = (E + 255) / 256;
    int nbc = (ND / 8 + (DD * DD) / 8 + 255) / 256;
    int nb1 = (E + S1E * 256 - 1) / (S1E * 256);

    // zero stat replicas + cnt (contiguous)
    hipMemsetAsync(csr, 0, (size_t)(2 * NREP * 128 + NN) * 4, stream);
    k_prep<<<nbh + nbc, 256, 0, stream>>>(ei, cnt, E, nbh, x, xb, W, wb);
    k_scanB<<<1, 1024, 0, stream>>>(cnt, bptr, bcur);
    k_scat1<<<nb1, 256, 0, stream>>>(ei, E, bcur, ebuck);
    k_scat2<<<NB, 256, 0, stream>>>(ebuck, bptr, ptr0, srow);
    k_gather<<<NN / 4, 256, 0, stream>>>(xb, srow, ptr0, cnt, aggb);
    k_gemm<<<(NN + 63) / 64, 256, 0, stream>>>((const ushort*)aggb, (const ushort*)wb,
                                               (ushort*)hb, csr, cqr);
    k_red<<<1, 256, 0, stream>>>(csr, cqr, colsum, colsumsq);
    k_final<<<ND / (256 * 4), 256, 0, stream>>>(hb, xb, gamma, beta,
                                                colsum, colsumsq, out, out_size);
}